// Round 13
// baseline (566.956 us; speedup 1.0000x reference)
//
#include <hip/hip_runtime.h>
#include <math.h>

#define NL 8
#define NP 512
#define NC 64
#define NF 128
#define NALL 192
#define NRAY (NL * NP)
#define HID 128

typedef _Float16 half8 __attribute__((ext_vector_type(8)));
typedef _Float16 half4v __attribute__((ext_vector_type(4)));
typedef float floatx16 __attribute__((ext_vector_type(16)));
typedef unsigned long long ull;

#define MFMA(a, b, c) __builtin_amdgcn_mfma_f32_32x32x16_f16((a), (b), (c), 0, 0, 0)

__device__ __forceinline__ float dcoarse_at(int i) {
    float t = (float)i * 0.015625f; // i/64, exact in fp32
    return 1e-3f * (1.0f - t) + 0.5f * t;
}

__device__ __forceinline__ floatx16 fzero16() {
    floatx16 z;
#pragma unroll
    for (int i = 0; i < 16; ++i) z[i] = 0.f;
    return z;
}
__device__ __forceinline__ half8 hzero8() {
    half8 z;
#pragma unroll
    for (int i = 0; i < 8; ++i) z[i] = (_Float16)0.f;
    return z;
}

// Wsp layout (per layer L in {0:w1, 1:w2}, plane p in {hi,lo}):
//   Wsp[(L*2+p)*16384 + f],  f = (((jb*8+ks)*2+lhi)*32 + l31)*8 + i
//   holding split(w[(ks*16+lhi*8+i)*128 + (jb*32+l31)]).
__global__ void prep_kernel(const float* __restrict__ w1, const float* __restrict__ w2,
                            _Float16* __restrict__ Wsp) {
    int f = blockIdx.x * 256 + threadIdx.x;   // [0, 16384)
    int layer = blockIdx.y;
    const float* w = layer ? w2 : w1;
    int i = f & 7, l31 = (f >> 3) & 31, lhi = (f >> 8) & 1, ks = (f >> 9) & 7, jb = f >> 12;
    int j = jb * 32 + l31;
    int k = ks * 16 + lhi * 8 + i;
    float v = w[k * 128 + j];
    _Float16 hi = (_Float16)v;
    Wsp[(layer * 2 + 0) * 16384 + f] = hi;
    Wsp[(layer * 2 + 1) * 16384 + f] = (_Float16)(v - (float)hi);
}

// FULLY FUSED pipeline: block = 2 rays, zero cross-block dependencies.
//   round 0: MLP on the 2 rays' 128 coarse points -> sdfC (LDS)
//   sample  : waves 0-1, one ray each (cdf scans, binary search, KV bitonic
//             sort) -> dF[256], perm[384] (LDS)
//   round 1: MLP on ray A's 128 fine points -> sdfF[0..128) (LDS)
//   round 2: MLP on ray B's 128 fine points -> sdfF[128..256) (LDS)
//   finish  : waves 0-1, one ray each -> out[2b+wv]
// MLP round = r10's best-measured structure (dual-plane LDS H, true-quadrant
// waves, 16B-chunk XOR swizzle, B layer-resident, A streamed from Wsp).
// Rationale (r12 post-mortem): ~78us of r12's 279 was grid-wide drain between
// kernels (not per-launch cost — r2 had 4 launches, ~0 gap); full fusion
// removes every grid-wide sync and all intermediate global traffic.
template<int FASTW>
__global__ __launch_bounds__(256, 2) void mega_kernel(
    const float* __restrict__ pts, const float* __restrict__ lights,
    const float* __restrict__ u,
    const float* __restrict__ w0, const float* __restrict__ b0,
    const float* __restrict__ w1, const float* __restrict__ b1,
    const float* __restrict__ w2, const float* __restrict__ b2,
    const float* __restrict__ w3, const float* __restrict__ b3,
    const _Float16* __restrict__ Wsp,
    float* __restrict__ out)
{
    __shared__ __align__(16) _Float16 Hhi[128 * 128];   // 32 KB
    __shared__ __align__(16) _Float16 Hlo[128 * 128];   // 32 KB
    __shared__ _Float16 Xs[6 * 128];     // coords hi/lo      1.5 KB
    __shared__ float P2[2 * 128];        // L4 partials        1 KB
    __shared__ float sdfC[128];          // coarse sdf, 2 rays 0.5 KB
    __shared__ float sdfF[256];          // fine sdf, 2 rays   1 KB
    __shared__ float dF[256];            // fine depths        1 KB
    __shared__ unsigned char perm[2 * NALL];  // sorted provenance 0.375 KB

    const int tid = threadIdx.x;
    const int lane = tid & 63;
    const int wv = tid >> 6;
    const int jh = wv & 1, mh = wv >> 1;
    const int l31 = lane & 31, lhi = lane >> 5;
    const int rayA = blockIdx.x * 2;
    const int m0 = mh * 64;              // this wave's 64-pt half

    auto haddr = [&](int m, int k0) {
        return m * 128 + ((((k0 >> 3) ^ (m & 15)) << 3) | (k0 & 7));
    };

    floatx16 acc[2][2];   // [jt][mt]
    half8 bh[2][8], bl[2][8];   // [mt][ks], 128 VGPR resident

    auto store_tile = [&](const floatx16& a, int jt, int mt, const float* __restrict__ bias) {
        int m = m0 + mt * 32 + l31;
#pragma unroll
        for (int g = 0; g < 4; ++g) {
            int jg = jh * 64 + jt * 32 + 8 * g + 4 * lhi;
            half4v hq, lq;
#pragma unroll
            for (int q = 0; q < 4; ++q) {
                float v = fmaxf(a[g * 4 + q] + bias[jg + q], 0.f);
                _Float16 hi = (_Float16)v;
                hq[q] = hi;
                lq[q] = (_Float16)(v - (float)hi);
            }
            int ad = haddr(m, jg);
            *(half4v*)&Hhi[ad] = hq;
            *(half4v*)&Hlo[ad] = lq;
        }
    };

    auto ldA = [&](int L, int jt, int ks, half8& ah, half8& al) {
        if (FASTW) {
            int off = ((((jh * 2 + jt) * 8 + ks) * 2 + lhi) * 32 + l31) * 8;
            ah = *(const half8*)&Wsp[(L * 2 + 0) * 16384 + off];
            al = *(const half8*)&Wsp[(L * 2 + 1) * 16384 + off];
        } else {
            const float* w = L ? w2 : w1;
            int j = jh * 64 + jt * 32 + l31, k0 = ks * 16 + lhi * 8;
#pragma unroll
            for (int i = 0; i < 8; ++i) {
                float v = w[(k0 + i) * 128 + j];
                _Float16 hi = (_Float16)v;
                ah[i] = hi;
                al[i] = (_Float16)(v - (float)hi);
            }
        }
    };

    auto gemm = [&](int L) {
#pragma unroll
        for (int mt = 0; mt < 2; ++mt) {
            int m = m0 + mt * 32 + l31;
#pragma unroll
            for (int ks = 0; ks < 8; ++ks) {
                int ad = haddr(m, ks * 16 + lhi * 8);
                bh[mt][ks] = *(const half8*)&Hhi[ad];
                bl[mt][ks] = *(const half8*)&Hlo[ad];
            }
        }
#pragma unroll
        for (int jt = 0; jt < 2; ++jt)
#pragma unroll
            for (int mt = 0; mt < 2; ++mt) acc[jt][mt] = fzero16();
#pragma unroll
        for (int ks = 0; ks < 8; ++ks) {
            half8 ah[2], al[2];
            ldA(L, 0, ks, ah[0], al[0]);
            ldA(L, 1, ks, ah[1], al[1]);
#pragma unroll
            for (int jt = 0; jt < 2; ++jt)
#pragma unroll
                for (int mt = 0; mt < 2; ++mt) acc[jt][mt] = MFMA(al[jt], bh[mt][ks], acc[jt][mt]);
#pragma unroll
            for (int jt = 0; jt < 2; ++jt)
#pragma unroll
                for (int mt = 0; mt < 2; ++mt) acc[jt][mt] = MFMA(ah[jt], bl[mt][ks], acc[jt][mt]);
#pragma unroll
            for (int jt = 0; jt < 2; ++jt)
#pragma unroll
                for (int mt = 0; mt < 2; ++mt) acc[jt][mt] = MFMA(ah[jt], bh[mt][ks], acc[jt][mt]);
        }
    };

#pragma unroll 1
    for (int rnd = 0; rnd < 3; ++rnd) {
        // ---- phase A: per-point coords, split to fp16 hi/lo in LDS
        if (tid < 128) {
            int ray; float d;
            if (rnd == 0) { ray = rayA + (tid >> 6); d = dcoarse_at(tid & 63); }
            else          { ray = rayA + (rnd - 1);  d = dF[(rnd - 1) * 128 + tid]; }
            int l = ray >> 9, p = ray & (NP - 1);
            float px = pts[p * 3 + 0], py = pts[p * 3 + 1], pz = pts[p * 3 + 2];
            float dx = lights[l * 3 + 0] - px, dy = lights[l * 3 + 1] - py, dz = lights[l * 3 + 2] - pz;
            float n = sqrtf(dx * dx + dy * dy + dz * dz);
            dx /= n; dy /= n; dz /= n;
            float xc[3] = { px + d * dx, py + d * dy, pz + d * dz };
#pragma unroll
            for (int c = 0; c < 3; ++c) {
                _Float16 h = (_Float16)xc[c];
                Xs[c * 128 + tid] = h;
                Xs[(3 + c) * 128 + tid] = (_Float16)(xc[c] - (float)h);
            }
        }
        __syncthreads();

        // ---- Layer 1: 3->128 as one K=16 MFMA step (k>=3 zero-padded)
        {
            half8 a1h[2], a1l[2], bh1[2], bl1[2];
#pragma unroll
            for (int jt = 0; jt < 2; ++jt) { a1h[jt] = hzero8(); a1l[jt] = hzero8(); }
#pragma unroll
            for (int mt = 0; mt < 2; ++mt) { bh1[mt] = hzero8(); bl1[mt] = hzero8(); }
            if (lhi == 0) {
#pragma unroll
                for (int jt = 0; jt < 2; ++jt) {
                    int j = jh * 64 + jt * 32 + l31;
#pragma unroll
                    for (int c = 0; c < 3; ++c) {
                        float v = w0[c * 128 + j];
                        _Float16 hi = (_Float16)v;
                        a1h[jt][c] = hi;
                        a1l[jt][c] = (_Float16)(v - (float)hi);
                    }
                }
#pragma unroll
                for (int mt = 0; mt < 2; ++mt) {
                    int m = m0 + mt * 32 + l31;
#pragma unroll
                    for (int c = 0; c < 3; ++c) {
                        bh1[mt][c] = Xs[c * 128 + m];
                        bl1[mt][c] = Xs[(3 + c) * 128 + m];
                    }
                }
            }
#pragma unroll
            for (int jt = 0; jt < 2; ++jt)
#pragma unroll
                for (int mt = 0; mt < 2; ++mt) acc[jt][mt] = fzero16();
#pragma unroll
            for (int jt = 0; jt < 2; ++jt)
#pragma unroll
                for (int mt = 0; mt < 2; ++mt) acc[jt][mt] = MFMA(a1l[jt], bh1[mt], acc[jt][mt]);
#pragma unroll
            for (int jt = 0; jt < 2; ++jt)
#pragma unroll
                for (int mt = 0; mt < 2; ++mt) acc[jt][mt] = MFMA(a1h[jt], bl1[mt], acc[jt][mt]);
#pragma unroll
            for (int jt = 0; jt < 2; ++jt)
#pragma unroll
                for (int mt = 0; mt < 2; ++mt) acc[jt][mt] = MFMA(a1h[jt], bh1[mt], acc[jt][mt]);
#pragma unroll
            for (int jt = 0; jt < 2; ++jt)
#pragma unroll
                for (int mt = 0; mt < 2; ++mt) store_tile(acc[jt][mt], jt, mt, b0);
        }
        __syncthreads();   // H1 visible

        // ---- Layer 2: H1 -> H2 (in place, barriered)
        gemm(0);
        __syncthreads();   // all waves done reading H1
#pragma unroll
        for (int jt = 0; jt < 2; ++jt)
#pragma unroll
            for (int mt = 0; mt < 2; ++mt) store_tile(acc[jt][mt], jt, mt, b1);
        __syncthreads();   // H2 visible

        // ---- Layer 3 (+ Layer 4 reduce, no write-back)
        gemm(1);
#pragma unroll
        for (int mt = 0; mt < 2; ++mt) {
            float p = 0.f;
#pragma unroll
            for (int jt = 0; jt < 2; ++jt)
#pragma unroll
                for (int g = 0; g < 4; ++g) {
                    int jg = jh * 64 + jt * 32 + 8 * g + 4 * lhi;
#pragma unroll
                    for (int q = 0; q < 4; ++q) {
                        float v = fmaxf(acc[jt][mt][g * 4 + q] + b2[jg + q], 0.f);
                        p = fmaf(v, w3[jg + q], p);
                    }
                }
            p += __shfl_xor(p, 32);
            if (lane < 32) P2[jh * 128 + m0 + mt * 32 + l31] = p;
        }
        __syncthreads();
        if (tid < 128) {
            float s = b3[0] + P2[tid] + P2[128 + tid];
            if (rnd == 0) sdfC[tid] = s;
            else          sdfF[(rnd - 1) * 128 + tid] = s;
        }
        __syncthreads();

        if (rnd == 0) {
            // ==== fused SAMPLE: waves 0-1, one ray each ====
            if (wv < 2) {
                const int ray = rayA + wv;
                float sv = sdfC[wv * 64 + lane];
                float c = 1.0f / (1.0f + expf(-100.0f * sv));
                float cn = __shfl_down(c, 1);
                bool valid = lane < 63;
                float a = valid ? fmaxf((c - cn) / (c + 1e-10f), 0.f) : 0.f;
                float sh = valid ? (1.f - a + 1e-10f) : 1.f;
                float ps = sh;
#pragma unroll
                for (int off = 1; off < 64; off <<= 1) { float o = __shfl_up(ps, off); if (lane >= off) ps *= o; }
                float T = __shfl_up(ps, 1);
                if (lane == 0) T = 1.f;
                float w = valid ? (a * T + 1e-5f) : 0.f;
                float wsum = w;
#pragma unroll
                for (int off = 1; off < 64; off <<= 1) wsum += __shfl_xor(wsum, off);
                float pdf = w / wsum;
                float cs = pdf;
#pragma unroll
                for (int off = 1; off < 64; off <<= 1) { float o = __shfl_up(cs, off); if (lane >= off) cs += o; }
                float cdfv = __shfl_up(cs, 1);
                if (lane == 0) cdfv = 0.f;   // cdf[lane], strictly increasing

                float df[2];
#pragma unroll
                for (int t = 0; t < 2; ++t) {
                    float uu = u[ray * NF + t * 64 + lane];
                    int lo = 0;
#pragma unroll
                    for (int b = 32; b >= 1; b >>= 1) {
                        float cm = __shfl(cdfv, lo + b);
                        if (uu >= cm) lo += b;
                    }
                    int above = min(lo + 1, NC - 1);
                    float cb = __shfl(cdfv, lo), ca = __shfl(cdfv, above);
                    float bb = dcoarse_at(lo), ba = dcoarse_at(above);
                    float denom = ca - cb;
                    if (denom < 1e-5f) denom = 1.f;
                    float tt = (uu - cb) / denom;
                    df[t] = bb + tt * (ba - bb);
                    dF[wv * 128 + t * 64 + lane] = df[t];
                }

                // key-value bitonic sort: key = float-bits(d)<<32 | idx
                ull v[4];
                v[0] = ((ull)__float_as_uint(dcoarse_at(lane)) << 32) | (unsigned)lane;
                v[1] = ((ull)__float_as_uint(df[0]) << 32) | (unsigned)(64 + lane);
                v[2] = ((ull)__float_as_uint(df[1]) << 32) | (unsigned)(128 + lane);
                v[3] = ((ull)0x7F800000u << 32) | 255u;   // +inf pad
                for (int k = 2; k <= 256; k <<= 1) {
                    for (int j = k >> 1; j > 0; j >>= 1) {
                        if (j >= 64) {
                            int tj = j >> 6;
#pragma unroll
                            for (int t = 0; t < 4; ++t) {
                                if ((t & tj) == 0) {
                                    int t2 = t ^ tj;
                                    bool asc = (((t * 64) & k) == 0);
                                    ull x = v[t], y = v[t2];
                                    bool sw = asc ? (x > y) : (x < y);
                                    if (sw) { v[t] = y; v[t2] = x; }
                                }
                            }
                        } else {
#pragma unroll
                            for (int t = 0; t < 4; ++t) {
                                int i = t * 64 + lane;
                                ull other = __shfl_xor(v[t], j);
                                bool lower = (lane & j) == 0;
                                bool asc = ((i & k) == 0);
                                bool takeMin = (lower == asc);
                                ull mn = v[t] < other ? v[t] : other;
                                ull mx = v[t] < other ? other : v[t];
                                v[t] = takeMin ? mn : mx;
                            }
                        }
                    }
                }
#pragma unroll
                for (int t = 0; t < 3; ++t)
                    perm[wv * NALL + t * 64 + lane] = (unsigned char)(v[t] & 0xFFu);
            }
            __syncthreads();   // dF/perm visible to all waves
        }
    }

    // ==== fused FINISH: waves 0-1, one ray each ====
    if (wv < 2) {
        const unsigned char* P = perm + wv * NALL;
        float c[4];
#pragma unroll
        for (int t = 0; t < 4; ++t) {
            int i = lane * 3 + t;
            if (i < NALL) {
                int idx = P[i];
                float s = (idx < 64) ? sdfC[wv * 64 + idx] : sdfF[wv * 128 + (idx - 64)];
                c[t] = 1.0f / (1.0f + expf(-100.0f * s));
            } else c[t] = 0.f;
        }
        float a[3], s[3];
#pragma unroll
        for (int t = 0; t < 3; ++t) {
            int i = lane * 3 + t;
            if (i < NALL - 1) {
                a[t] = fmaxf((c[t] - c[t + 1]) / (c[t] + 1e-10f), 0.f);
                s[t] = 1.f - a[t] + 1e-10f;
            } else { a[t] = 0.f; s[t] = 1.f; }
        }
        float chunk = s[0] * s[1] * s[2];
        float ps = chunk;
#pragma unroll
        for (int off = 1; off < 64; off <<= 1) {
            float o = __shfl_up(ps, off);
            if (lane >= off) ps *= o;
        }
        float T = __shfl_up(ps, 1);
        if (lane == 0) T = 1.f;
        float occ = a[0] * T;
        T *= s[0]; occ = fmaf(a[1], T, occ);
        T *= s[1]; occ = fmaf(a[2], T, occ);
#pragma unroll
        for (int off = 1; off < 64; off <<= 1) occ += __shfl_xor(occ, off);
        if (lane == 0) out[rayA + wv] = 1.f - occ;
    }
}

extern "C" void kernel_launch(void* const* d_in, const int* in_sizes, int n_in,
                              void* d_out, int out_size, void* d_ws, size_t ws_size,
                              hipStream_t stream) {
    const float* pts = (const float*)d_in[0];
    const float* lights = (const float*)d_in[1];
    const float* u = (const float*)d_in[2];
    const float* w0 = (const float*)d_in[3];
    const float* b0 = (const float*)d_in[4];
    const float* w1 = (const float*)d_in[5];
    const float* b1 = (const float*)d_in[6];
    const float* w2 = (const float*)d_in[7];
    const float* b2 = (const float*)d_in[8];
    const float* w3 = (const float*)d_in[9];
    const float* b3 = (const float*)d_in[10];
    float* out = (float*)d_out;

    // workspace: only the split-weight cache (128 KB)
    _Float16* Wsp = (_Float16*)d_ws;
    const bool fast = ws_size >= (size_t)4 * 16384 * sizeof(_Float16);

    if (fast) {
        prep_kernel<<<dim3(64, 2), 256, 0, stream>>>(w1, w2, Wsp);
        mega_kernel<1><<<NRAY / 2, 256, 0, stream>>>(
            pts, lights, u, w0, b0, w1, b1, w2, b2, w3, b3, Wsp, out);
    } else {
        mega_kernel<0><<<NRAY / 2, 256, 0, stream>>>(
            pts, lights, u, w0, b0, w1, b1, w2, b2, w3, b3, nullptr, out);
    }
}

// Round 14
// 273.876 us; speedup vs baseline: 2.0701x; 2.0701x over previous
//
#include <hip/hip_runtime.h>
#include <math.h>

#define NL 8
#define NP 512
#define NC 64
#define NF 128
#define NALL 192
#define NRAY (NL * NP)
#define HID 128

typedef _Float16 half8 __attribute__((ext_vector_type(8)));
typedef _Float16 half4v __attribute__((ext_vector_type(4)));
typedef float floatx16 __attribute__((ext_vector_type(16)));
typedef unsigned long long ull;

#define MFMA(a, b, c) __builtin_amdgcn_mfma_f32_32x32x16_f16((a), (b), (c), 0, 0, 0)

__device__ __forceinline__ float dcoarse_at(int i) {
    float t = (float)i * 0.015625f; // i/64, exact in fp32
    return 1e-3f * (1.0f - t) + 0.5f * t;
}

__device__ __forceinline__ floatx16 fzero16() {
    floatx16 z;
#pragma unroll
    for (int i = 0; i < 16; ++i) z[i] = 0.f;
    return z;
}
__device__ __forceinline__ half8 hzero8() {
    half8 z;
#pragma unroll
    for (int i = 0; i < 8; ++i) z[i] = (_Float16)0.f;
    return z;
}

// Wsp layout (per layer L in {0:w1, 1:w2}, plane p in {hi,lo}):
//   Wsp[(L*2+p)*16384 + f],  f = (((jb*8+ks)*2+lhi)*32 + l31)*8 + i
//   holding split(w[(ks*16+lhi*8+i)*128 + (jb*32+l31)]).
__global__ void prep_kernel(const float* __restrict__ w1, const float* __restrict__ w2,
                            _Float16* __restrict__ Wsp) {
    int f = blockIdx.x * 256 + threadIdx.x;   // [0, 16384)
    int layer = blockIdx.y;
    const float* w = layer ? w2 : w1;
    int i = f & 7, l31 = (f >> 3) & 31, lhi = (f >> 8) & 1, ks = (f >> 9) & 7, jb = f >> 12;
    int j = jb * 32 + l31;
    int k = ks * 16 + lhi * 8 + i;
    float v = w[k * 128 + j];
    _Float16 hi = (_Float16)v;
    Wsp[(layer * 2 + 0) * 16384 + f] = hi;
    Wsp[(layer * 2 + 1) * 16384 + f] = (_Float16)(v - (float)hi);
}

// Fused 4-layer MLP over 128 points per block, split-fp16 MFMA — r10's best
// measured structure (dual-plane LDS H, true-quadrant waves, 16B-chunk XOR
// swizzle, B layer-resident, A streamed coalesced from Wsp).
//   MODE 0 (coarse): block = 2 whole rays. After the epilogue, waves 0-1 run
//     the per-ray SAMPLE in-block (r12 measured this fusion spill-free,
//     VGPR 96). Writes sdf_c, d_fine, perm8.
//   MODE 1 (fine): pure r10 fine MLP — writes sdf_f; finish stays a separate
//     kernel (r12 measured fine+finish fusion at +10us on the fine dispatch).
template<int MODE, int FASTW>
__global__ __launch_bounds__(256, 2) void mlp_kernel(
    const float* __restrict__ pts, const float* __restrict__ lights,
    const float* __restrict__ u,
    float* __restrict__ d_fine, unsigned char* __restrict__ perm8,
    const float* __restrict__ w0, const float* __restrict__ b0,
    const float* __restrict__ w1, const float* __restrict__ b1,
    const float* __restrict__ w2, const float* __restrict__ b2,
    const float* __restrict__ w3, const float* __restrict__ b3,
    const _Float16* __restrict__ Wsp,
    float* __restrict__ sdf_out)
{
    __shared__ __align__(16) _Float16 Hhi[128 * 128];
    __shared__ __align__(16) _Float16 Hlo[128 * 128];
    __shared__ _Float16 Xs[6 * 128];   // hi c0,c1,c2 then lo c0,c1,c2
    __shared__ float P2[2 * 128];      // partial sums; then [0..127] = final sdf

    const int tid = threadIdx.x;
    const int lane = tid & 63;
    const int wv = tid >> 6;
    const int jh = wv & 1, mh = wv >> 1;
    const int l31 = lane & 31, lhi = lane >> 5;
    const int base = blockIdx.x * 128;

    // ---- phase A: per-point coords, split to fp16 hi/lo in LDS
    if (tid < 128) {
        int pt = base + tid;
        int ray; float d;
        if (MODE == 0) { ray = pt >> 6; d = dcoarse_at(pt & 63); }
        else           { ray = pt >> 7; d = d_fine[pt]; }
        int l = ray >> 9, p = ray & (NP - 1);
        float px = pts[p * 3 + 0], py = pts[p * 3 + 1], pz = pts[p * 3 + 2];
        float dx = lights[l * 3 + 0] - px, dy = lights[l * 3 + 1] - py, dz = lights[l * 3 + 2] - pz;
        float n = sqrtf(dx * dx + dy * dy + dz * dz);
        dx /= n; dy /= n; dz /= n;
        float xc[3] = { px + d * dx, py + d * dy, pz + d * dz };
#pragma unroll
        for (int c = 0; c < 3; ++c) {
            _Float16 h = (_Float16)xc[c];
            Xs[c * 128 + tid] = h;
            Xs[(3 + c) * 128 + tid] = (_Float16)(xc[c] - (float)h);
        }
    }
    __syncthreads();

    const int m0 = mh * 64;            // this wave's 64-pt half

    auto haddr = [&](int m, int k0) {
        return m * 128 + ((((k0 >> 3) ^ (m & 15)) << 3) | (k0 & 7));
    };

    auto store_tile = [&](const floatx16& a, int jt, int mt, const float* __restrict__ bias) {
        int m = m0 + mt * 32 + l31;
#pragma unroll
        for (int g = 0; g < 4; ++g) {
            int jg = jh * 64 + jt * 32 + 8 * g + 4 * lhi;
            half4v hq, lq;
#pragma unroll
            for (int q = 0; q < 4; ++q) {
                float v = fmaxf(a[g * 4 + q] + bias[jg + q], 0.f);
                _Float16 hi = (_Float16)v;
                hq[q] = hi;
                lq[q] = (_Float16)(v - (float)hi);
            }
            int ad = haddr(m, jg);
            *(half4v*)&Hhi[ad] = hq;
            *(half4v*)&Hlo[ad] = lq;
        }
    };

    floatx16 acc[2][2];   // [jt][mt]

    // ---- Layer 1: 3->128 as one K=16 MFMA step (k>=3 zero-padded)
    {
        half8 a1h[2], a1l[2], bh1[2], bl1[2];
#pragma unroll
        for (int jt = 0; jt < 2; ++jt) { a1h[jt] = hzero8(); a1l[jt] = hzero8(); }
#pragma unroll
        for (int mt = 0; mt < 2; ++mt) { bh1[mt] = hzero8(); bl1[mt] = hzero8(); }
        if (lhi == 0) {
#pragma unroll
            for (int jt = 0; jt < 2; ++jt) {
                int j = jh * 64 + jt * 32 + l31;
#pragma unroll
                for (int c = 0; c < 3; ++c) {
                    float v = w0[c * 128 + j];
                    _Float16 hi = (_Float16)v;
                    a1h[jt][c] = hi;
                    a1l[jt][c] = (_Float16)(v - (float)hi);
                }
            }
#pragma unroll
            for (int mt = 0; mt < 2; ++mt) {
                int m = m0 + mt * 32 + l31;
#pragma unroll
                for (int c = 0; c < 3; ++c) {
                    bh1[mt][c] = Xs[c * 128 + m];
                    bl1[mt][c] = Xs[(3 + c) * 128 + m];
                }
            }
        }
#pragma unroll
        for (int jt = 0; jt < 2; ++jt)
#pragma unroll
            for (int mt = 0; mt < 2; ++mt) acc[jt][mt] = fzero16();
#pragma unroll
        for (int jt = 0; jt < 2; ++jt)
#pragma unroll
            for (int mt = 0; mt < 2; ++mt) acc[jt][mt] = MFMA(a1l[jt], bh1[mt], acc[jt][mt]);
#pragma unroll
        for (int jt = 0; jt < 2; ++jt)
#pragma unroll
            for (int mt = 0; mt < 2; ++mt) acc[jt][mt] = MFMA(a1h[jt], bl1[mt], acc[jt][mt]);
#pragma unroll
        for (int jt = 0; jt < 2; ++jt)
#pragma unroll
            for (int mt = 0; mt < 2; ++mt) acc[jt][mt] = MFMA(a1h[jt], bh1[mt], acc[jt][mt]);
#pragma unroll
        for (int jt = 0; jt < 2; ++jt)
#pragma unroll
            for (int mt = 0; mt < 2; ++mt) store_tile(acc[jt][mt], jt, mt, b0);
    }
    __syncthreads();   // H1 visible

    auto ldA = [&](int L, int jt, int ks, half8& ah, half8& al) {
        if (FASTW) {
            int off = ((((jh * 2 + jt) * 8 + ks) * 2 + lhi) * 32 + l31) * 8;
            ah = *(const half8*)&Wsp[(L * 2 + 0) * 16384 + off];
            al = *(const half8*)&Wsp[(L * 2 + 1) * 16384 + off];
        } else {
            const float* w = L ? w2 : w1;
            int j = jh * 64 + jt * 32 + l31, k0 = ks * 16 + lhi * 8;
#pragma unroll
            for (int i = 0; i < 8; ++i) {
                float v = w[(k0 + i) * 128 + j];
                _Float16 hi = (_Float16)v;
                ah[i] = hi;
                al[i] = (_Float16)(v - (float)hi);
            }
        }
    };

    {
        half8 bh[2][8], bl[2][8];   // [mt][ks], 128 VGPR resident

        auto gemm = [&](int L) {
#pragma unroll
            for (int mt = 0; mt < 2; ++mt) {
                int m = m0 + mt * 32 + l31;
#pragma unroll
                for (int ks = 0; ks < 8; ++ks) {
                    int ad = haddr(m, ks * 16 + lhi * 8);
                    bh[mt][ks] = *(const half8*)&Hhi[ad];
                    bl[mt][ks] = *(const half8*)&Hlo[ad];
                }
            }
#pragma unroll
            for (int jt = 0; jt < 2; ++jt)
#pragma unroll
                for (int mt = 0; mt < 2; ++mt) acc[jt][mt] = fzero16();
#pragma unroll
            for (int ks = 0; ks < 8; ++ks) {
                half8 ah[2], al[2];
                ldA(L, 0, ks, ah[0], al[0]);
                ldA(L, 1, ks, ah[1], al[1]);
#pragma unroll
                for (int jt = 0; jt < 2; ++jt)
#pragma unroll
                    for (int mt = 0; mt < 2; ++mt) acc[jt][mt] = MFMA(al[jt], bh[mt][ks], acc[jt][mt]);
#pragma unroll
                for (int jt = 0; jt < 2; ++jt)
#pragma unroll
                    for (int mt = 0; mt < 2; ++mt) acc[jt][mt] = MFMA(ah[jt], bl[mt][ks], acc[jt][mt]);
#pragma unroll
                for (int jt = 0; jt < 2; ++jt)
#pragma unroll
                    for (int mt = 0; mt < 2; ++mt) acc[jt][mt] = MFMA(ah[jt], bh[mt][ks], acc[jt][mt]);
            }
        };

        // ---- Layer 2: H1 -> H2 (in place, barriered)
        gemm(0);
        __syncthreads();   // all waves done reading H1
#pragma unroll
        for (int jt = 0; jt < 2; ++jt)
#pragma unroll
            for (int mt = 0; mt < 2; ++mt) store_tile(acc[jt][mt], jt, mt, b1);
        __syncthreads();   // H2 visible

        // ---- Layer 3 (+ Layer 4 reduce, no write-back)
        gemm(1);
    }
#pragma unroll
    for (int mt = 0; mt < 2; ++mt) {
        float p = 0.f;
#pragma unroll
        for (int jt = 0; jt < 2; ++jt)
#pragma unroll
            for (int g = 0; g < 4; ++g) {
                int jg = jh * 64 + jt * 32 + 8 * g + 4 * lhi;
#pragma unroll
                for (int q = 0; q < 4; ++q) {
                    float v = fmaxf(acc[jt][mt][g * 4 + q] + b2[jg + q], 0.f);
                    p = fmaf(v, w3[jg + q], p);
                }
            }
        p += __shfl_xor(p, 32);
        if (lane < 32) P2[jh * 128 + m0 + mt * 32 + l31] = p;
    }
    __syncthreads();
    if (tid < 128) {
        float s = b3[0] + P2[tid] + P2[128 + tid];   // reads own slots only
        sdf_out[base + tid] = s;
        if (MODE == 0) P2[tid] = s;
    }

    if (MODE == 0) {
        __syncthreads();
        // ======== fused SAMPLE: waves 0-1, one ray each (rays = 2b, 2b+1) ====
        if (wv < 2) {
            const int ray = blockIdx.x * 2 + wv;
            float sv = P2[wv * 64 + lane];
            float c = 1.0f / (1.0f + expf(-100.0f * sv));
            float cn = __shfl_down(c, 1);
            bool valid = lane < 63;
            float a = valid ? fmaxf((c - cn) / (c + 1e-10f), 0.f) : 0.f;
            float sh = valid ? (1.f - a + 1e-10f) : 1.f;
            float ps = sh;
#pragma unroll
            for (int off = 1; off < 64; off <<= 1) { float o = __shfl_up(ps, off); if (lane >= off) ps *= o; }
            float T = __shfl_up(ps, 1);
            if (lane == 0) T = 1.f;
            float w = valid ? (a * T + 1e-5f) : 0.f;
            float wsum = w;
#pragma unroll
            for (int off = 1; off < 64; off <<= 1) wsum += __shfl_xor(wsum, off);
            float pdf = w / wsum;
            float cs = pdf;
#pragma unroll
            for (int off = 1; off < 64; off <<= 1) { float o = __shfl_up(cs, off); if (lane >= off) cs += o; }
            float cdfv = __shfl_up(cs, 1);
            if (lane == 0) cdfv = 0.f;   // cdf[lane], strictly increasing

            float df[2];
#pragma unroll
            for (int t = 0; t < 2; ++t) {
                float uu = u[ray * NF + t * 64 + lane];
                int lo = 0;
#pragma unroll
                for (int b = 32; b >= 1; b >>= 1) {
                    float cm = __shfl(cdfv, lo + b);
                    if (uu >= cm) lo += b;
                }
                int above = min(lo + 1, NC - 1);
                float cb = __shfl(cdfv, lo), ca = __shfl(cdfv, above);
                float bb = dcoarse_at(lo), ba = dcoarse_at(above);
                float denom = ca - cb;
                if (denom < 1e-5f) denom = 1.f;
                float tt = (uu - cb) / denom;
                df[t] = bb + tt * (ba - bb);
                d_fine[ray * 128 + t * 64 + lane] = df[t];
            }

            // key-value bitonic sort: key = float-bits(d)<<32 | idx
            ull v[4];
            v[0] = ((ull)__float_as_uint(dcoarse_at(lane)) << 32) | (unsigned)lane;
            v[1] = ((ull)__float_as_uint(df[0]) << 32) | (unsigned)(64 + lane);
            v[2] = ((ull)__float_as_uint(df[1]) << 32) | (unsigned)(128 + lane);
            v[3] = ((ull)0x7F800000u << 32) | 255u;   // +inf pad
            for (int k = 2; k <= 256; k <<= 1) {
                for (int j = k >> 1; j > 0; j >>= 1) {
                    if (j >= 64) {
                        int tj = j >> 6;
#pragma unroll
                        for (int t = 0; t < 4; ++t) {
                            if ((t & tj) == 0) {
                                int t2 = t ^ tj;
                                bool asc = (((t * 64) & k) == 0);
                                ull x = v[t], y = v[t2];
                                bool sw = asc ? (x > y) : (x < y);
                                if (sw) { v[t] = y; v[t2] = x; }
                            }
                        }
                    } else {
#pragma unroll
                        for (int t = 0; t < 4; ++t) {
                            int i = t * 64 + lane;
                            ull other = __shfl_xor(v[t], j);
                            bool lower = (lane & j) == 0;
                            bool asc = ((i & k) == 0);
                            bool takeMin = (lower == asc);
                            ull mn = v[t] < other ? v[t] : other;
                            ull mx = v[t] < other ? other : v[t];
                            v[t] = takeMin ? mn : mx;
                        }
                    }
                }
            }
#pragma unroll
            for (int t = 0; t < 3; ++t)
                perm8[ray * NALL + t * 64 + lane] = (unsigned char)(v[t] & 0xFFu);
        }
    }
}

// One wave per ray: gather sdf via permutation (idx<64 -> coarse, else fine),
// then chunked (3/lane) product scan for T, occu sum, out = 1-occu.
__global__ __launch_bounds__(256) void finish_kernel(
    const float* __restrict__ sdf_c, const float* __restrict__ sdf_f,
    const unsigned char* __restrict__ perm8, float* __restrict__ out) {
    int lane = threadIdx.x & 63, wv = threadIdx.x >> 6;
    int ray = blockIdx.x * 4 + wv;
    const unsigned char* P = perm8 + (size_t)ray * NALL;
    float c[4];
#pragma unroll
    for (int t = 0; t < 4; ++t) {
        int i = lane * 3 + t;
        if (i < NALL) {
            int idx = P[i];
            float s = (idx < 64) ? sdf_c[ray * NC + idx] : sdf_f[ray * 128 + (idx - 64)];
            c[t] = 1.0f / (1.0f + expf(-100.0f * s));
        } else c[t] = 0.f;
    }
    float a[3], s[3];
#pragma unroll
    for (int t = 0; t < 3; ++t) {
        int i = lane * 3 + t;
        if (i < NALL - 1) {
            a[t] = fmaxf((c[t] - c[t + 1]) / (c[t] + 1e-10f), 0.f);
            s[t] = 1.f - a[t] + 1e-10f;
        } else { a[t] = 0.f; s[t] = 1.f; }
    }
    float chunk = s[0] * s[1] * s[2];
    float ps = chunk;
#pragma unroll
    for (int off = 1; off < 64; off <<= 1) {
        float o = __shfl_up(ps, off);
        if (lane >= off) ps *= o;
    }
    float T = __shfl_up(ps, 1);
    if (lane == 0) T = 1.f;
    float occ = a[0] * T;
    T *= s[0]; occ = fmaf(a[1], T, occ);
    T *= s[1]; occ = fmaf(a[2], T, occ);
#pragma unroll
    for (int off = 1; off < 64; off <<= 1) occ += __shfl_xor(occ, off);
    if (lane == 0) out[ray] = 1.f - occ;
}

extern "C" void kernel_launch(void* const* d_in, const int* in_sizes, int n_in,
                              void* d_out, int out_size, void* d_ws, size_t ws_size,
                              hipStream_t stream) {
    const float* pts = (const float*)d_in[0];
    const float* lights = (const float*)d_in[1];
    const float* u = (const float*)d_in[2];
    const float* w0 = (const float*)d_in[3];
    const float* b0 = (const float*)d_in[4];
    const float* w1 = (const float*)d_in[5];
    const float* b1 = (const float*)d_in[6];
    const float* w2 = (const float*)d_in[7];
    const float* b2 = (const float*)d_in[8];
    const float* w3 = (const float*)d_in[9];
    const float* b3 = (const float*)d_in[10];
    float* out = (float*)d_out;

    // ws layout:
    //   sdf_c  : NRAY*64  f32 (1.00 MB)  coarse sdf — read by finish
    //   sdf_f  : NRAY*128 f32 (2.00 MB)  fine sdf
    //   d_fine : NRAY*128 f32 (2.00 MB)  raw fine sample depths
    //   perm8  : NRAY*192 u8  (0.75 MB)  sorted provenance permutation
    //   Wsp    : 4*16384  f16 (0.125 MB) split weights
    char* wsb = (char*)d_ws;
    float* sdf_c = (float*)wsb;
    float* sdf_f = (float*)(wsb + (size_t)NRAY * NC * 4);
    float* d_fine = (float*)(wsb + (size_t)NRAY * (NC + 128) * 4);
    unsigned char* perm8 = (unsigned char*)(wsb + (size_t)NRAY * (NC + 256) * 4);
    _Float16* Wsp = (_Float16*)(wsb + (size_t)NRAY * (NC + 256) * 4 + (size_t)NRAY * NALL);
    const size_t need = (size_t)NRAY * (NC + 256) * 4 + (size_t)NRAY * NALL
                      + (size_t)4 * 16384 * sizeof(_Float16);
    const bool fast = ws_size >= need;

    if (fast) {
        prep_kernel<<<dim3(64, 2), 256, 0, stream>>>(w1, w2, Wsp);
        mlp_kernel<0, 1><<<(NRAY * NC) / 128, 256, 0, stream>>>(
            pts, lights, u, d_fine, perm8,
            w0, b0, w1, b1, w2, b2, w3, b3, Wsp, sdf_c);
        mlp_kernel<1, 1><<<(NRAY * 128) / 128, 256, 0, stream>>>(
            pts, lights, u, d_fine, perm8,
            w0, b0, w1, b1, w2, b2, w3, b3, Wsp, sdf_f);
    } else {
        mlp_kernel<0, 0><<<(NRAY * NC) / 128, 256, 0, stream>>>(
            pts, lights, u, d_fine, perm8,
            w0, b0, w1, b1, w2, b2, w3, b3, nullptr, sdf_c);
        mlp_kernel<1, 0><<<(NRAY * 128) / 128, 256, 0, stream>>>(
            pts, lights, u, d_fine, perm8,
            w0, b0, w1, b1, w2, b2, w3, b3, nullptr, sdf_f);
    }
    finish_kernel<<<NRAY / 4, 256, 0, stream>>>(sdf_c, sdf_f, perm8, out);
}

// Round 15
// 250.847 us; speedup vs baseline: 2.2602x; 1.0918x over previous
//
#include <hip/hip_runtime.h>
#include <math.h>

#define NL 8
#define NP 512
#define NC 64
#define NF 128
#define NALL 192
#define NRAY (NL * NP)
#define HID 128

typedef _Float16 half8 __attribute__((ext_vector_type(8)));
typedef _Float16 half4v __attribute__((ext_vector_type(4)));
typedef float floatx16 __attribute__((ext_vector_type(16)));
typedef unsigned long long ull;

#define MFMA(a, b, c) __builtin_amdgcn_mfma_f32_32x32x16_f16((a), (b), (c), 0, 0, 0)

// FINAL (champion r10 configuration, 253.3 us measured):
//  - split-fp16 3-MFMA emulation of fp32 (absmax 0.0 vs numpy ref)
//  - fused 4-layer MLP, 128 pts/block, true-quadrant waves, dual-plane LDS H
//    with 16B-chunk XOR swizzle; A-weights streamed coalesced from prepacked Wsp
//  - coarse sdf deduplicated: fine MLP runs only the 128 new points/ray;
//    finish gathers via the sort's provenance permutation
//  - separate sample/finish wave-per-ray kernels (all fusion variants measured
//    slower: r12 279, r13 567, r14 274)
// Plateau: MLP kernels at ~37% of MFMA ceiling = documented 2-barrier
// LDS-staged K-loop plateau; beyond requires asm-level vmcnt interleaving.

__device__ __forceinline__ float dcoarse_at(int i) {
    float t = (float)i * 0.015625f; // i/64, exact in fp32
    return 1e-3f * (1.0f - t) + 0.5f * t;
}

__device__ __forceinline__ floatx16 fzero16() {
    floatx16 z;
#pragma unroll
    for (int i = 0; i < 16; ++i) z[i] = 0.f;
    return z;
}
__device__ __forceinline__ half8 hzero8() {
    half8 z;
#pragma unroll
    for (int i = 0; i < 8; ++i) z[i] = (_Float16)0.f;
    return z;
}

// Wsp layout (per layer L in {0:w1, 1:w2}, plane p in {hi,lo}):
//   Wsp[(L*2+p)*16384 + f],  f = (((jb*8+ks)*2+lhi)*32 + l31)*8 + i
//   holding split(w[(ks*16+lhi*8+i)*128 + (jb*32+l31)]).
__global__ void prep_kernel(const float* __restrict__ w1, const float* __restrict__ w2,
                            _Float16* __restrict__ Wsp) {
    int f = blockIdx.x * 256 + threadIdx.x;   // [0, 16384)
    int layer = blockIdx.y;
    const float* w = layer ? w2 : w1;
    int i = f & 7, l31 = (f >> 3) & 31, lhi = (f >> 8) & 1, ks = (f >> 9) & 7, jb = f >> 12;
    int j = jb * 32 + l31;
    int k = ks * 16 + lhi * 8 + i;
    float v = w[k * 128 + j];
    _Float16 hi = (_Float16)v;
    Wsp[(layer * 2 + 0) * 16384 + f] = hi;
    Wsp[(layer * 2 + 1) * 16384 + f] = (_Float16)(v - (float)hi);
}

// Fused 4-layer MLP over 128 points per block, split-fp16 MFMA.
// MODE 0: coarse points (ray = pt>>6). MODE 1: fine points only (ray = pt>>7).
template<int MODE, int FASTW>
__global__ __launch_bounds__(256, 2) void mlp_kernel(
    const float* __restrict__ pts, const float* __restrict__ lights,
    const float* __restrict__ d_fine,
    const float* __restrict__ w0, const float* __restrict__ b0,
    const float* __restrict__ w1, const float* __restrict__ b1,
    const float* __restrict__ w2, const float* __restrict__ b2,
    const float* __restrict__ w3, const float* __restrict__ b3,
    const _Float16* __restrict__ Wsp,
    float* __restrict__ sdf_out)
{
    __shared__ __align__(16) _Float16 Hhi[128 * 128];
    __shared__ __align__(16) _Float16 Hlo[128 * 128];
    __shared__ _Float16 Xs[6 * 128];   // hi c0,c1,c2 then lo c0,c1,c2
    __shared__ float P2[2 * 128];      // [jh][m]

    const int tid = threadIdx.x;
    const int lane = tid & 63;
    const int wv = tid >> 6;
    const int jh = wv & 1, mh = wv >> 1;
    const int l31 = lane & 31, lhi = lane >> 5;
    const int base = blockIdx.x * 128;

    // ---- phase A: per-point coords, split to fp16 hi/lo in LDS
    if (tid < 128) {
        int pt = base + tid;
        int ray; float d;
        if (MODE == 0) { ray = pt >> 6; d = dcoarse_at(pt & 63); }
        else           { ray = pt >> 7; d = d_fine[pt]; }
        int l = ray >> 9, p = ray & (NP - 1);
        float px = pts[p * 3 + 0], py = pts[p * 3 + 1], pz = pts[p * 3 + 2];
        float dx = lights[l * 3 + 0] - px, dy = lights[l * 3 + 1] - py, dz = lights[l * 3 + 2] - pz;
        float n = sqrtf(dx * dx + dy * dy + dz * dz);
        dx /= n; dy /= n; dz /= n;
        float xc[3] = { px + d * dx, py + d * dy, pz + d * dz };
#pragma unroll
        for (int c = 0; c < 3; ++c) {
            _Float16 h = (_Float16)xc[c];
            Xs[c * 128 + tid] = h;
            Xs[(3 + c) * 128 + tid] = (_Float16)(xc[c] - (float)h);
        }
    }
    __syncthreads();

    const int m0 = mh * 64;                 // this wave's 64-pt half

    auto haddr = [&](int m, int k0) {
        return m * 128 + ((((k0 >> 3) ^ (m & 15)) << 3) | (k0 & 7));
    };

    auto store_tile = [&](const floatx16& a, int jt, int mt, const float* __restrict__ bias) {
        int m = m0 + mt * 32 + l31;
#pragma unroll
        for (int g = 0; g < 4; ++g) {
            int jg = jh * 64 + jt * 32 + 8 * g + 4 * lhi;
            half4v hq, lq;
#pragma unroll
            for (int q = 0; q < 4; ++q) {
                float v = fmaxf(a[g * 4 + q] + bias[jg + q], 0.f);
                _Float16 hi = (_Float16)v;
                hq[q] = hi;
                lq[q] = (_Float16)(v - (float)hi);
            }
            int ad = haddr(m, jg);
            *(half4v*)&Hhi[ad] = hq;
            *(half4v*)&Hlo[ad] = lq;
        }
    };

    floatx16 acc[2][2];   // [jt][mt]

    // ---- Layer 1: 3->128 as one K=16 MFMA step (k>=3 zero-padded)
    {
        half8 a1h[2], a1l[2], bh1[2], bl1[2];
#pragma unroll
        for (int jt = 0; jt < 2; ++jt) { a1h[jt] = hzero8(); a1l[jt] = hzero8(); }
#pragma unroll
        for (int mt = 0; mt < 2; ++mt) { bh1[mt] = hzero8(); bl1[mt] = hzero8(); }
        if (lhi == 0) {
#pragma unroll
            for (int jt = 0; jt < 2; ++jt) {
                int j = jh * 64 + jt * 32 + l31;
#pragma unroll
                for (int c = 0; c < 3; ++c) {
                    float v = w0[c * 128 + j];
                    _Float16 hi = (_Float16)v;
                    a1h[jt][c] = hi;
                    a1l[jt][c] = (_Float16)(v - (float)hi);
                }
            }
#pragma unroll
            for (int mt = 0; mt < 2; ++mt) {
                int m = m0 + mt * 32 + l31;
#pragma unroll
                for (int c = 0; c < 3; ++c) {
                    bh1[mt][c] = Xs[c * 128 + m];
                    bl1[mt][c] = Xs[(3 + c) * 128 + m];
                }
            }
        }
#pragma unroll
        for (int jt = 0; jt < 2; ++jt)
#pragma unroll
            for (int mt = 0; mt < 2; ++mt) acc[jt][mt] = fzero16();
#pragma unroll
        for (int jt = 0; jt < 2; ++jt)
#pragma unroll
            for (int mt = 0; mt < 2; ++mt) acc[jt][mt] = MFMA(a1l[jt], bh1[mt], acc[jt][mt]);
#pragma unroll
        for (int jt = 0; jt < 2; ++jt)
#pragma unroll
            for (int mt = 0; mt < 2; ++mt) acc[jt][mt] = MFMA(a1h[jt], bl1[mt], acc[jt][mt]);
#pragma unroll
        for (int jt = 0; jt < 2; ++jt)
#pragma unroll
            for (int mt = 0; mt < 2; ++mt) acc[jt][mt] = MFMA(a1h[jt], bh1[mt], acc[jt][mt]);
#pragma unroll
        for (int jt = 0; jt < 2; ++jt)
#pragma unroll
            for (int mt = 0; mt < 2; ++mt) store_tile(acc[jt][mt], jt, mt, b0);
    }
    __syncthreads();   // H1 visible

    auto ldA = [&](int L, int jt, int ks, half8& ah, half8& al) {
        if (FASTW) {
            int off = ((((jh * 2 + jt) * 8 + ks) * 2 + lhi) * 32 + l31) * 8;
            ah = *(const half8*)&Wsp[(L * 2 + 0) * 16384 + off];
            al = *(const half8*)&Wsp[(L * 2 + 1) * 16384 + off];
        } else {
            const float* w = L ? w2 : w1;
            int j = jh * 64 + jt * 32 + l31, k0 = ks * 16 + lhi * 8;
#pragma unroll
            for (int i = 0; i < 8; ++i) {
                float v = w[(k0 + i) * 128 + j];
                _Float16 hi = (_Float16)v;
                ah[i] = hi;
                al[i] = (_Float16)(v - (float)hi);
            }
        }
    };

    half8 bh[2][8], bl[2][8];   // [mt][ks], 128 VGPR resident

    auto gemm = [&](int L) {
#pragma unroll
        for (int mt = 0; mt < 2; ++mt) {
            int m = m0 + mt * 32 + l31;
#pragma unroll
            for (int ks = 0; ks < 8; ++ks) {
                int ad = haddr(m, ks * 16 + lhi * 8);
                bh[mt][ks] = *(const half8*)&Hhi[ad];
                bl[mt][ks] = *(const half8*)&Hlo[ad];
            }
        }
#pragma unroll
        for (int jt = 0; jt < 2; ++jt)
#pragma unroll
            for (int mt = 0; mt < 2; ++mt) acc[jt][mt] = fzero16();
#pragma unroll
        for (int ks = 0; ks < 8; ++ks) {
            half8 ah[2], al[2];
            ldA(L, 0, ks, ah[0], al[0]);
            ldA(L, 1, ks, ah[1], al[1]);
#pragma unroll
            for (int jt = 0; jt < 2; ++jt)
#pragma unroll
                for (int mt = 0; mt < 2; ++mt) acc[jt][mt] = MFMA(al[jt], bh[mt][ks], acc[jt][mt]);
#pragma unroll
            for (int jt = 0; jt < 2; ++jt)
#pragma unroll
                for (int mt = 0; mt < 2; ++mt) acc[jt][mt] = MFMA(ah[jt], bl[mt][ks], acc[jt][mt]);
#pragma unroll
            for (int jt = 0; jt < 2; ++jt)
#pragma unroll
                for (int mt = 0; mt < 2; ++mt) acc[jt][mt] = MFMA(ah[jt], bh[mt][ks], acc[jt][mt]);
        }
    };

    // ---- Layer 2: H1 -> H2 (in place, barriered)
    gemm(0);
    __syncthreads();   // all waves done reading H1
#pragma unroll
    for (int jt = 0; jt < 2; ++jt)
#pragma unroll
        for (int mt = 0; mt < 2; ++mt) store_tile(acc[jt][mt], jt, mt, b1);
    __syncthreads();   // H2 visible

    // ---- Layer 3 (+ Layer 4 reduce, no write-back)
    gemm(1);
#pragma unroll
    for (int mt = 0; mt < 2; ++mt) {
        float p = 0.f;
#pragma unroll
        for (int jt = 0; jt < 2; ++jt)
#pragma unroll
            for (int g = 0; g < 4; ++g) {
                int jg = jh * 64 + jt * 32 + 8 * g + 4 * lhi;
#pragma unroll
                for (int q = 0; q < 4; ++q) {
                    float v = fmaxf(acc[jt][mt][g * 4 + q] + b2[jg + q], 0.f);
                    p = fmaf(v, w3[jg + q], p);
                }
            }
        p += __shfl_xor(p, 32);
        if (lane < 32) P2[jh * 128 + m0 + mt * 32 + l31] = p;
    }
    __syncthreads();
    if (tid < 128) sdf_out[base + tid] = b3[0] + P2[tid] + P2[128 + tid];
}

// One wave per ray: shfl scans for cdf, shfl binary-search for sample_pdf
// (exact searchsorted-count semantics on strictly-increasing cdf), then a
// 256-item bitonic KEY-VALUE sort (key = float-bits(d)<<32 | idx). Outputs
// raw fine d's (for the MLP) and the sorted provenance permutation.
__global__ __launch_bounds__(256) void sample_kernel(
    const float* __restrict__ sdf_c, const float* __restrict__ u,
    float* __restrict__ d_fine, unsigned char* __restrict__ perm8) {
    const int lane = threadIdx.x & 63, wv = threadIdx.x >> 6;
    const int ray = blockIdx.x * 4 + wv;

    float sv = sdf_c[ray * NC + lane];
    float c = 1.0f / (1.0f + expf(-100.0f * sv));
    float cn = __shfl_down(c, 1);
    bool valid = lane < 63;
    float a = valid ? fmaxf((c - cn) / (c + 1e-10f), 0.f) : 0.f;
    float sh = valid ? (1.f - a + 1e-10f) : 1.f;
    float ps = sh;
#pragma unroll
    for (int off = 1; off < 64; off <<= 1) { float o = __shfl_up(ps, off); if (lane >= off) ps *= o; }
    float T = __shfl_up(ps, 1);
    if (lane == 0) T = 1.f;
    float w = valid ? (a * T + 1e-5f) : 0.f;
    float wsum = w;
#pragma unroll
    for (int off = 1; off < 64; off <<= 1) wsum += __shfl_xor(wsum, off);
    float pdf = w / wsum;
    float cs = pdf;
#pragma unroll
    for (int off = 1; off < 64; off <<= 1) { float o = __shfl_up(cs, off); if (lane >= off) cs += o; }
    float cdfv = __shfl_up(cs, 1);
    if (lane == 0) cdfv = 0.f;    // cdf[lane], strictly increasing, cdf[0]=0

    float df[2];
#pragma unroll
    for (int t = 0; t < 2; ++t) {
        float uu = u[ray * NF + t * 64 + lane];
        int lo = 0;
#pragma unroll
        for (int b = 32; b >= 1; b >>= 1) {
            float cm = __shfl(cdfv, lo + b);
            if (uu >= cm) lo += b;
        }
        int above = min(lo + 1, NC - 1);
        float cb = __shfl(cdfv, lo), ca = __shfl(cdfv, above);
        float bb = dcoarse_at(lo), ba = dcoarse_at(above);
        float denom = ca - cb;
        if (denom < 1e-5f) denom = 1.f;
        float tt = (uu - cb) / denom;
        df[t] = bb + tt * (ba - bb);
        d_fine[ray * 128 + t * 64 + lane] = df[t];
    }

    ull v[4];
    v[0] = ((ull)__float_as_uint(dcoarse_at(lane)) << 32) | (unsigned)lane;
    v[1] = ((ull)__float_as_uint(df[0]) << 32) | (unsigned)(64 + lane);
    v[2] = ((ull)__float_as_uint(df[1]) << 32) | (unsigned)(128 + lane);
    v[3] = ((ull)0x7F800000u << 32) | 255u;   // +inf pad
    for (int k = 2; k <= 256; k <<= 1) {
        for (int j = k >> 1; j > 0; j >>= 1) {
            if (j >= 64) {
                int tj = j >> 6;
#pragma unroll
                for (int t = 0; t < 4; ++t) {
                    if ((t & tj) == 0) {
                        int t2 = t ^ tj;
                        bool asc = (((t * 64) & k) == 0);
                        ull x = v[t], y = v[t2];
                        bool sw = asc ? (x > y) : (x < y);
                        if (sw) { v[t] = y; v[t2] = x; }
                    }
                }
            } else {
#pragma unroll
                for (int t = 0; t < 4; ++t) {
                    int i = t * 64 + lane;
                    ull other = __shfl_xor(v[t], j);
                    bool lower = (lane & j) == 0;
                    bool asc = ((i & k) == 0);
                    bool takeMin = (lower == asc);
                    ull mn = v[t] < other ? v[t] : other;
                    ull mx = v[t] < other ? other : v[t];
                    v[t] = takeMin ? mn : mx;
                }
            }
        }
    }
#pragma unroll
    for (int t = 0; t < 3; ++t)
        perm8[ray * NALL + t * 64 + lane] = (unsigned char)(v[t] & 0xFFu);
}

// One wave per ray: gather sdf via permutation (idx<64 -> coarse, else fine),
// then chunked (3/lane) product scan for T, occu sum, out = 1-occu.
__global__ __launch_bounds__(256) void finish_kernel(
    const float* __restrict__ sdf_c, const float* __restrict__ sdf_f,
    const unsigned char* __restrict__ perm8, float* __restrict__ out) {
    int lane = threadIdx.x & 63, wv = threadIdx.x >> 6;
    int ray = blockIdx.x * 4 + wv;
    const unsigned char* P = perm8 + (size_t)ray * NALL;
    float c[4];
#pragma unroll
    for (int t = 0; t < 4; ++t) {
        int i = lane * 3 + t;
        if (i < NALL) {
            int idx = P[i];
            float s = (idx < 64) ? sdf_c[ray * NC + idx] : sdf_f[ray * 128 + (idx - 64)];
            c[t] = 1.0f / (1.0f + expf(-100.0f * s));
        } else c[t] = 0.f;
    }
    float a[3], s[3];
#pragma unroll
    for (int t = 0; t < 3; ++t) {
        int i = lane * 3 + t;
        if (i < NALL - 1) {
            a[t] = fmaxf((c[t] - c[t + 1]) / (c[t] + 1e-10f), 0.f);
            s[t] = 1.f - a[t] + 1e-10f;
        } else { a[t] = 0.f; s[t] = 1.f; }
    }
    float chunk = s[0] * s[1] * s[2];
    float ps = chunk;
#pragma unroll
    for (int off = 1; off < 64; off <<= 1) {
        float o = __shfl_up(ps, off);
        if (lane >= off) ps *= o;
    }
    float T = __shfl_up(ps, 1);
    if (lane == 0) T = 1.f;
    float occ = a[0] * T;
    T *= s[0]; occ = fmaf(a[1], T, occ);
    T *= s[1]; occ = fmaf(a[2], T, occ);
#pragma unroll
    for (int off = 1; off < 64; off <<= 1) occ += __shfl_xor(occ, off);
    if (lane == 0) out[ray] = 1.f - occ;
}

extern "C" void kernel_launch(void* const* d_in, const int* in_sizes, int n_in,
                              void* d_out, int out_size, void* d_ws, size_t ws_size,
                              hipStream_t stream) {
    const float* pts = (const float*)d_in[0];
    const float* lights = (const float*)d_in[1];
    const float* u = (const float*)d_in[2];
    const float* w0 = (const float*)d_in[3];
    const float* b0 = (const float*)d_in[4];
    const float* w1 = (const float*)d_in[5];
    const float* b1 = (const float*)d_in[6];
    const float* w2 = (const float*)d_in[7];
    const float* b2 = (const float*)d_in[8];
    const float* w3 = (const float*)d_in[9];
    const float* b3 = (const float*)d_in[10];
    float* out = (float*)d_out;

    // ws layout:
    //   sdf_c  : NRAY*64  f32   coarse sdf — persists to finish
    //   sdf_f  : NRAY*128 f32   fine sdf
    //   d_fine : NRAY*128 f32   raw fine sample depths
    //   perm8  : NRAY*192 u8    sorted provenance permutation
    //   Wsp    : 4*16384  f16   split weights
    char* wsb = (char*)d_ws;
    float* sdf_c = (float*)wsb;
    float* sdf_f = (float*)(wsb + (size_t)NRAY * NC * 4);
    float* d_fine = (float*)(wsb + (size_t)NRAY * (NC + 128) * 4);
    unsigned char* perm8 = (unsigned char*)(wsb + (size_t)NRAY * (NC + 256) * 4);
    _Float16* Wsp = (_Float16*)(wsb + (size_t)NRAY * (NC + 256) * 4 + (size_t)NRAY * NALL);
    const size_t need = (size_t)NRAY * (NC + 256) * 4 + (size_t)NRAY * NALL
                      + (size_t)4 * 16384 * sizeof(_Float16);
    const bool fast = ws_size >= need;

    if (fast) {
        prep_kernel<<<dim3(64, 2), 256, 0, stream>>>(w1, w2, Wsp);
        mlp_kernel<0, 1><<<(NRAY * NC) / 128, 256, 0, stream>>>(
            pts, lights, nullptr, w0, b0, w1, b1, w2, b2, w3, b3, Wsp, sdf_c);
        sample_kernel<<<NRAY / 4, 256, 0, stream>>>(sdf_c, u, d_fine, perm8);
        mlp_kernel<1, 1><<<(NRAY * 128) / 128, 256, 0, stream>>>(
            pts, lights, d_fine, w0, b0, w1, b1, w2, b2, w3, b3, Wsp, sdf_f);
    } else {
        mlp_kernel<0, 0><<<(NRAY * NC) / 128, 256, 0, stream>>>(
            pts, lights, nullptr, w0, b0, w1, b1, w2, b2, w3, b3, nullptr, sdf_c);
        sample_kernel<<<NRAY / 4, 256, 0, stream>>>(sdf_c, u, d_fine, perm8);
        mlp_kernel<1, 0><<<(NRAY * 128) / 128, 256, 0, stream>>>(
            pts, lights, d_fine, w0, b0, w1, b1, w2, b2, w3, b3, nullptr, sdf_f);
    }
    finish_kernel<<<NRAY / 4, 256, 0, stream>>>(sdf_c, sdf_f, perm8, out);
}